// Round 2
// 299.792 us; speedup vs baseline: 1.0019x; 1.0019x over previous
//
#include <hip/hip_runtime.h>
#include <math.h>

#define B 16
#define C 2
#define T 2000
#define F 257
#define NC 100           // chunks per (b,f)
#define L  (T / NC)      // 20 timesteps per chunk

#define RES_SIZE   (B * C * T * F * 2)   // 32,896,000
#define OFF_SFINAL (RES_SIZE)            // + B*F
#define OFF_SMOOTH (RES_SIZE + B * F)    // + B*T*F

#define N_CARRY (B * NC * F)             // 411,200 threads (phase-1 ch0 / phase-2)
#define G0      ((N_CARRY + 255) / 256)  // 1607 blocks
#define SLAB4   (T * F * 2 / 4)          // 257,000 float4 per (b, ch1) slab
#define N_V4    (B * SLAB4)              // 4,112,000 float4 threads for ch1
#define G1      ((N_V4 + 255) / 256)     // 16,063 blocks

__device__ __forceinline__ float sigmoidf_(float x) {
    return 1.0f / (1.0f + expf(-x));
}

// Phase 1 (fused): blocks [0,G0) compute per-chunk carries for channel 0;
// blocks [G0, G0+G1) do the channel-1 elementwise path with float4 loads.
// The big independent ch1 streaming work fills the machine while the
// lower-parallelism carries phase runs.
__global__ __launch_bounds__(256) void k_phase1(const float* __restrict__ input,
                                                const float* __restrict__ alpha_param,
                                                const float* __restrict__ weights,
                                                const float* __restrict__ bias,
                                                float* __restrict__ carry,
                                                float* __restrict__ out) {
    int bid = blockIdx.x;
    if (bid < G0) {
        // ---- chunk carries: recurrence with s=0 over L steps ----
        int tid = bid * 256 + threadIdx.x;
        if (tid >= N_CARRY) return;
        int f = tid % F;
        int r = tid / F;
        int c = r % NC;
        int b = r / NC;

        float a = sigmoidf_(alpha_param[f]);
        float beta = 1.0f - a;

        const float2* inp = (const float2*)input
                          + ((size_t)(b * C + 0) * T + (size_t)c * L) * F + f;
        float s = 0.0f;
#pragma unroll
        for (int t = 0; t < L; ++t) {
            float2 v = inp[(size_t)t * F];
            s = beta * s + a * (v.x * v.x + v.y * v.y);
        }
        carry[((size_t)b * NC + c) * F + f] = s;
    } else {
        // ---- channel 1: pure elementwise, float4-vectorized ----
        int idx = (bid - G0) * 256 + threadIdx.x;
        if (idx >= N_V4) return;
        int b   = idx / SLAB4;
        int rem = idx - b * SLAB4;

        const float4* ip = (const float4*)(input + ((size_t)(b * C + 1) * T) * F * 2) + rem;
        float4 v = *ip;

        int e  = rem * 2;              // float2 index within slab
        int f0 = e % F;                // magic-mul, F=257 constant
        int f1 = (f0 + 1 == F) ? 0 : (f0 + 1);

        float w0 = weights[F + f0], w1 = weights[F + f1];
        float q0 = bias[F + f0],    q1 = bias[F + f1];

        float inv0 = 1.0f / (sqrtf(v.x * v.x + v.y * v.y) + 1e-8f);
        float inv1 = 1.0f / (sqrtf(v.z * v.z + v.w * v.w) + 1e-8f);

        float4 rr;
        rr.x = v.x * inv0 * w0 + q0;
        rr.y = v.y * inv0 * w0 + q0;
        rr.z = v.z * inv1 * w1 + q1;
        rr.w = v.w * inv1 * w1 + q1;

        float4* rp = (float4*)(out + ((size_t)(b * C + 1) * T) * F * 2) + rem;
        *rp = rr;
    }
}

// Phase 2 (fused scan + final): each (b,c,f) thread folds its own chunk-start
// state from the carries (replaces the 17-workgroup k_scan bubble and the
// chunkstart buffer), then runs the exact per-step recurrence, writing
// res ch0 + smooth; the c==NC-1 threads end holding s_final.
__global__ __launch_bounds__(256) void k_phase2(const float* __restrict__ input,
                                                const float* __restrict__ s_1,
                                                const float* __restrict__ alpha_param,
                                                const float* __restrict__ weights,
                                                const float* __restrict__ bias,
                                                const float* __restrict__ carry,
                                                float* __restrict__ out) {
    int tid = blockIdx.x * 256 + threadIdx.x;
    if (tid >= N_CARRY) return;
    int f = tid % F;
    int r = tid / F;
    int c = r % NC;
    int b = r / NC;

    float a = sigmoidf_(alpha_param[f]);
    float beta = 1.0f - a;
    float bL = 1.0f;
#pragma unroll
    for (int i = 0; i < L; ++i) bL *= beta;
    float bL2 = bL * bL;
    float bL3 = bL2 * bL;
    float bL4 = bL2 * bL2;

    // redundant per-thread prefix over carries (L2-resident, 1.6 MB buffer);
    // 4-way unrolled: 4 independent loads per iteration, short dep chain
    const float* cp = carry + (size_t)b * NC * F + f;
    float s = s_1[b * F + f];
    int j = 0;
    for (; j + 4 <= c; j += 4) {
        float c0 = cp[(size_t)(j    ) * F];
        float c1 = cp[(size_t)(j + 1) * F];
        float c2 = cp[(size_t)(j + 2) * F];
        float c3 = cp[(size_t)(j + 3) * F];
        s = fmaf(bL4, s, fmaf(bL3, c0, fmaf(bL2, c1, fmaf(bL, c2, c3))));
    }
    for (; j < c; ++j) s = fmaf(bL, s, cp[(size_t)j * F]);

    float w0 = weights[f];   // channel 0
    float q0 = bias[f];

    const float2* inp = (const float2*)input
                      + ((size_t)(b * C + 0) * T + (size_t)c * L) * F + f;
    float2* res = (float2*)out
                + ((size_t)(b * C + 0) * T + (size_t)c * L) * F + f;
    float* smooth = out + OFF_SMOOTH + ((size_t)b * T + (size_t)c * L) * F + f;

#pragma unroll
    for (int t = 0; t < L; ++t) {
        float2 v = inp[(size_t)t * F];
        float x = v.x * v.x + v.y * v.y;
        s = beta * s + a * x;
        float sm = sqrtf(s);
        float inv = 1.0f / (sm + 1e-8f);
        float2 rr;
        rr.x = v.x * inv * w0 + q0;
        rr.y = v.y * inv * w0 + q0;
        res[(size_t)t * F] = rr;
        smooth[(size_t)t * F] = sm;
    }
    if (c == NC - 1) out[OFF_SFINAL + (size_t)b * F + f] = s;  // pre-sqrt state
}

extern "C" void kernel_launch(void* const* d_in, const int* in_sizes, int n_in,
                              void* d_out, int out_size, void* d_ws, size_t ws_size,
                              hipStream_t stream) {
    const float* input       = (const float*)d_in[0];
    const float* s_1         = (const float*)d_in[1];
    const float* weights     = (const float*)d_in[2];
    const float* bias        = (const float*)d_in[3];
    const float* alpha_param = (const float*)d_in[4];
    float* out = (float*)d_out;

    float* carry = (float*)d_ws;   // B*NC*F floats = 1.64 MB (fits prior ws budget)

    k_phase1<<<G0 + G1, 256, 0, stream>>>(input, alpha_param, weights, bias, carry, out);
    k_phase2<<<G0, 256, 0, stream>>>(input, s_1, alpha_param, weights, bias, carry, out);
}